// Round 1
// 124.168 us; speedup vs baseline: 1.0069x; 1.0069x over previous
//
#include <hip/hip_runtime.h>
#include <math.h>

#define SEQ_LEN   8192
#define HIDDEN    1024
#define NUM_SPANS 4096
#define MAX_W     32

typedef float f4v __attribute__((ext_vector_type(4)));

__device__ __forceinline__ float dot4(float4 a, float4 b) {
    return a.x * b.x + a.y * b.y + a.z * b.z + a.w * b.w;
}

// Non-temporal 16B store: output (50 MB) is never re-read; keep it out of L2
// so embedding rows stay resident.
__device__ __forceinline__ void nt_store4(float4* p, float4 v) {
    f4v x = { v.x, v.y, v.z, v.w };
    __builtin_nontemporal_store(x, (f4v*)p);
}

// One WAVE per span (4 spans per 256-thread block). Lane c owns output
// columns {4c..4c+3, +256, +512, +768} for the whole span:
//   - per row: 4 fully-coalesced float4 loads (1 KB per instruction),
//     dot against attn_w slices held in registers, 6-step __shfl_xor
//     butterfly -> wave-uniform score, online softmax, FMA into the
//     register accumulator. No LDS staging, no barriers at all.
//   - 1-row software pipeline (load row r+1 while computing row r).
//   - start row == pipeline row 0 registers, end row == final pipeline
//     registers -> the separate start/end fetches of the previous version
//     are gone, as are the clamped duplicate tail rows.
//   - softmax state (m, l, score) is wave-uniform, so the rescale branch
//     (only taken when the running max increases, ~log2(w) times/span)
//     is divergence-free.
__global__ __launch_bounds__(256, 4) void span_repr_kernel(
    const float* __restrict__ emb,      // (SEQ_LEN, HIDDEN)
    const int* __restrict__ starts,     // (NUM_SPANS,)
    const int* __restrict__ ends,       // (NUM_SPANS,)
    const float* __restrict__ attn_w,   // (HIDDEN,)
    const float* __restrict__ attn_b,   // (1,)
    float* __restrict__ out)            // (NUM_SPANS, 3*HIDDEN)
{
    const int tid = threadIdx.x;
    const int w2  = tid >> 6;           // wave id 0..3 -> span within block
    const int c   = tid & 63;           // lane
    const int s   = (blockIdx.x << 2) + w2;

    const int start = starts[s];
    const int wmax  = ends[s] - start;  // inclusive width-1, 0..31
    const float bias = attn_b[0];

    const float4* __restrict__ embr = (const float4*)emb + (size_t)start * 256;

    // per-lane attn_w slice: float4 indices c, c+64, c+128, c+192
    const float4* __restrict__ wv4 = (const float4*)attn_w;
    const float4 wv0 = wv4[c];
    const float4 wv1 = wv4[c + 64];
    const float4 wv2 = wv4[c + 128];
    const float4 wv3 = wv4[c + 192];

    float4* __restrict__ out4 = (float4*)(out + (size_t)s * (3 * HIDDEN));

    // row 0 (== start row)
    float4 v0 = embr[c];
    float4 v1 = embr[c + 64];
    float4 v2 = embr[c + 128];
    float4 v3 = embr[c + 192];

    nt_store4(&out4[c],       v0);
    nt_store4(&out4[c + 64],  v1);
    nt_store4(&out4[c + 128], v2);
    nt_store4(&out4[c + 192], v3);

    float4 a0 = make_float4(0.f, 0.f, 0.f, 0.f);
    float4 a1 = make_float4(0.f, 0.f, 0.f, 0.f);
    float4 a2 = make_float4(0.f, 0.f, 0.f, 0.f);
    float4 a3 = make_float4(0.f, 0.f, 0.f, 0.f);
    float m = -INFINITY;
    float l = 0.0f;

    for (int r = 0; r <= wmax; ++r) {
        // ---- issue next row's loads (last iter re-loads row wmax: L1 hit,
        //      and leaves v = end row for the epilogue) ----
        const float4* __restrict__ nr = embr + (size_t)min(r + 1, wmax) * 256;
        float4 n0 = nr[c];
        float4 n1 = nr[c + 64];
        float4 n2 = nr[c + 128];
        float4 n3 = nr[c + 192];
        __builtin_amdgcn_sched_barrier(0);   // pin loads above the compute

        // ---- score for row r (wave-uniform after butterfly) ----
        float p = dot4(v0, wv0) + dot4(v1, wv1) + dot4(v2, wv2) + dot4(v3, wv3);
        #pragma unroll
        for (int off = 32; off > 0; off >>= 1)
            p += __shfl_xor(p, off, 64);
        const float sc = p + bias;

        // ---- online softmax (rescale only when max grows; wave-uniform) --
        if (sc > m) {
            const float alpha = __expf(m - sc);   // m=-inf first row -> 0
            a0.x *= alpha; a0.y *= alpha; a0.z *= alpha; a0.w *= alpha;
            a1.x *= alpha; a1.y *= alpha; a1.z *= alpha; a1.w *= alpha;
            a2.x *= alpha; a2.y *= alpha; a2.z *= alpha; a2.w *= alpha;
            a3.x *= alpha; a3.y *= alpha; a3.z *= alpha; a3.w *= alpha;
            l *= alpha;
            m = sc;
        }
        const float e = __expf(sc - m);
        l += e;
        a0.x += e * v0.x; a0.y += e * v0.y; a0.z += e * v0.z; a0.w += e * v0.w;
        a1.x += e * v1.x; a1.y += e * v1.y; a1.z += e * v1.z; a1.w += e * v1.w;
        a2.x += e * v2.x; a2.y += e * v2.y; a2.z += e * v2.z; a2.w += e * v2.w;
        a3.x += e * v3.x; a3.y += e * v3.y; a3.z += e * v3.z; a3.w += e * v3.w;

        v0 = n0; v1 = n1; v2 = n2; v3 = n3;
    }

    // v now holds row wmax == end row
    nt_store4(&out4[256 + c],       v0);
    nt_store4(&out4[256 + c + 64],  v1);
    nt_store4(&out4[256 + c + 128], v2);
    nt_store4(&out4[256 + c + 192], v3);

    const float inv = 1.0f / l;                  // row 0 contributes e=1 -> l>0
    nt_store4(&out4[512 + c],
              make_float4(a0.x * inv, a0.y * inv, a0.z * inv, a0.w * inv));
    nt_store4(&out4[512 + c + 64],
              make_float4(a1.x * inv, a1.y * inv, a1.z * inv, a1.w * inv));
    nt_store4(&out4[512 + c + 128],
              make_float4(a2.x * inv, a2.y * inv, a2.z * inv, a2.w * inv));
    nt_store4(&out4[512 + c + 192],
              make_float4(a3.x * inv, a3.y * inv, a3.z * inv, a3.w * inv));
}

extern "C" void kernel_launch(void* const* d_in, const int* in_sizes, int n_in,
                              void* d_out, int out_size, void* d_ws, size_t ws_size,
                              hipStream_t stream) {
    const float* emb    = (const float*)d_in[0];
    const int*   starts = (const int*)d_in[1];
    const int*   ends   = (const int*)d_in[2];
    const float* attn_w = (const float*)d_in[3];
    const float* attn_b = (const float*)d_in[4];
    float* out = (float*)d_out;

    span_repr_kernel<<<NUM_SPANS / 4, 256, 0, stream>>>(emb, starts, ends, attn_w, attn_b, out);
}

// Round 2
// 112.968 us; speedup vs baseline: 1.1067x; 1.0991x over previous
//
#include <hip/hip_runtime.h>
#include <math.h>

#define SEQ_LEN   8192
#define HIDDEN    1024
#define NUM_SPANS 4096
#define MAX_W     32
#define NBLK      (NUM_SPANS / 4)   // 1024 main-kernel blocks
#define NXCD      8

typedef float f4v __attribute__((ext_vector_type(4)));

__device__ __forceinline__ float dot4(float4 a, float4 b) {
    return a.x * b.x + a.y * b.y + a.z * b.z + a.w * b.w;
}

// Non-temporal 16B store: output (50 MB) is never re-read; keep it out of
// L2/L3 so embedding rows stay resident.
__device__ __forceinline__ void nt_store4(float4* p, float4 v) {
    f4v x = { v.x, v.y, v.z, v.w };
    __builtin_nontemporal_store(x, (f4v*)p);
}

// ---------------------------------------------------------------------------
// Kernel 1: counting sort of span ids by start (1024 buckets of 8 rows).
// Single block, 1024 threads. Round-2 evidence: two structurally different
// main kernels both pin at 48 us with ~118 MB FETCH vs a 33.5 MB table --
// the bottleneck is L2 locality of the span->row gather, so reorder spans
// so that concurrently-running blocks touch neighboring rows.
// ---------------------------------------------------------------------------
__global__ __launch_bounds__(1024) void sort_spans_kernel(
    const int* __restrict__ starts,
    int* __restrict__ perm)             // (NUM_SPANS,) span ids, sorted by start
{
    __shared__ int hist[1024];
    __shared__ int base[1024];
    __shared__ int wsum[16];

    const int tid  = threadIdx.x;
    const int lane = tid & 63;
    const int wid  = tid >> 6;

    hist[tid] = 0;
    __syncthreads();

    #pragma unroll
    for (int i = tid; i < NUM_SPANS; i += 1024)
        atomicAdd(&hist[starts[i] >> 3], 1);
    __syncthreads();

    // exclusive scan over the 1024 buckets
    const int v = hist[tid];
    int sc = v;
    #pragma unroll
    for (int off = 1; off < 64; off <<= 1) {
        const int t = __shfl_up(sc, off, 64);
        if (lane >= off) sc += t;
    }
    if (lane == 63) wsum[wid] = sc;
    __syncthreads();
    if (wid == 0 && lane < 16) {
        int ws = wsum[lane];
        #pragma unroll
        for (int off = 1; off < 16; off <<= 1) {
            const int t = __shfl_up(ws, off, 64);
            if (lane >= off) ws += t;
        }
        wsum[lane] = ws;                 // inclusive wave sums
    }
    __syncthreads();
    const int waveOff = (wid == 0) ? 0 : wsum[wid - 1];
    base[tid] = waveOff + sc - v;        // exclusive prefix for bucket tid
    __syncthreads();

    hist[tid] = 0;                       // reuse as per-bucket counters
    __syncthreads();

    #pragma unroll
    for (int i = tid; i < NUM_SPANS; i += 1024) {
        const int b   = starts[i] >> 3;
        const int pos = base[b] + atomicAdd(&hist[b], 1);
        perm[pos] = i;
    }
}

// ---------------------------------------------------------------------------
// Kernel 2: one WAVE per span, 4 spans per block, spans taken in SORTED order
// with an XCD-aware mapping: blocks dispatch round-robin across the 8 XCDs
// (xcd = blockIdx % 8), so giving blockIdx.x its sorted slot as
// (blockIdx%8)*128 + blockIdx/8 hands each XCD a CONTIGUOUS eighth of the
// sorted spans -> per-XCD concurrent working set ~4.2 MB ~= its private L2.
// The 4 waves of a block process 4 consecutive sorted spans (heavily
// overlapping rows -> L1/L2 hits). Inner loop unchanged from round 1
// (register accumulators, no LDS, no barriers, 1-row pipeline).
// ---------------------------------------------------------------------------
__global__ __launch_bounds__(256, 4) void span_repr_kernel(
    const float* __restrict__ emb,      // (SEQ_LEN, HIDDEN)
    const int* __restrict__ starts,     // (NUM_SPANS,)
    const int* __restrict__ ends,       // (NUM_SPANS,)
    const float* __restrict__ attn_w,   // (HIDDEN,)
    const float* __restrict__ attn_b,   // (1,)
    const int* __restrict__ perm,       // (NUM_SPANS,) sorted span order
    float* __restrict__ out)            // (NUM_SPANS, 3*HIDDEN)
{
    const int tid = threadIdx.x;
    const int w2  = tid >> 6;           // wave id 0..3 -> span within block
    const int c   = tid & 63;           // lane

    // XCD-contiguous sorted slot for this block
    const int slot = (blockIdx.x & (NXCD - 1)) * (NBLK / NXCD) + (blockIdx.x >> 3);
    const int s    = perm[(slot << 2) + w2];

    const int start = starts[s];
    const int wmax  = ends[s] - start;  // inclusive width-1, 0..31
    const float bias = attn_b[0];

    const float4* __restrict__ embr = (const float4*)emb + (size_t)start * 256;

    // per-lane attn_w slice: float4 indices c, c+64, c+128, c+192
    const float4* __restrict__ wv4 = (const float4*)attn_w;
    const float4 wv0 = wv4[c];
    const float4 wv1 = wv4[c + 64];
    const float4 wv2 = wv4[c + 128];
    const float4 wv3 = wv4[c + 192];

    float4* __restrict__ out4 = (float4*)(out + (size_t)s * (3 * HIDDEN));

    // row 0 (== start row)
    float4 v0 = embr[c];
    float4 v1 = embr[c + 64];
    float4 v2 = embr[c + 128];
    float4 v3 = embr[c + 192];

    nt_store4(&out4[c],       v0);
    nt_store4(&out4[c + 64],  v1);
    nt_store4(&out4[c + 128], v2);
    nt_store4(&out4[c + 192], v3);

    float4 a0 = make_float4(0.f, 0.f, 0.f, 0.f);
    float4 a1 = make_float4(0.f, 0.f, 0.f, 0.f);
    float4 a2 = make_float4(0.f, 0.f, 0.f, 0.f);
    float4 a3 = make_float4(0.f, 0.f, 0.f, 0.f);
    float m = -INFINITY;
    float l = 0.0f;

    for (int r = 0; r <= wmax; ++r) {
        // issue next row's loads (last iter re-loads row wmax: L1 hit,
        // and leaves v = end row for the epilogue)
        const float4* __restrict__ nr = embr + (size_t)min(r + 1, wmax) * 256;
        float4 n0 = nr[c];
        float4 n1 = nr[c + 64];
        float4 n2 = nr[c + 128];
        float4 n3 = nr[c + 192];
        __builtin_amdgcn_sched_barrier(0);   // pin loads above the compute

        // score for row r (wave-uniform after butterfly)
        float p = dot4(v0, wv0) + dot4(v1, wv1) + dot4(v2, wv2) + dot4(v3, wv3);
        #pragma unroll
        for (int off = 32; off > 0; off >>= 1)
            p += __shfl_xor(p, off, 64);
        const float sc = p + bias;

        // online softmax (rescale only when max grows; wave-uniform)
        if (sc > m) {
            const float alpha = __expf(m - sc);   // m=-inf first row -> 0
            a0.x *= alpha; a0.y *= alpha; a0.z *= alpha; a0.w *= alpha;
            a1.x *= alpha; a1.y *= alpha; a1.z *= alpha; a1.w *= alpha;
            a2.x *= alpha; a2.y *= alpha; a2.z *= alpha; a2.w *= alpha;
            a3.x *= alpha; a3.y *= alpha; a3.z *= alpha; a3.w *= alpha;
            l *= alpha;
            m = sc;
        }
        const float e = __expf(sc - m);
        l += e;
        a0.x += e * v0.x; a0.y += e * v0.y; a0.z += e * v0.z; a0.w += e * v0.w;
        a1.x += e * v1.x; a1.y += e * v1.y; a1.z += e * v1.z; a1.w += e * v1.w;
        a2.x += e * v2.x; a2.y += e * v2.y; a2.z += e * v2.z; a2.w += e * v2.w;
        a3.x += e * v3.x; a3.y += e * v3.y; a3.z += e * v3.z; a3.w += e * v3.w;

        v0 = n0; v1 = n1; v2 = n2; v3 = n3;
    }

    // v now holds row wmax == end row
    nt_store4(&out4[256 + c],       v0);
    nt_store4(&out4[256 + c + 64],  v1);
    nt_store4(&out4[256 + c + 128], v2);
    nt_store4(&out4[256 + c + 192], v3);

    const float inv = 1.0f / l;                  // row 0 contributes e=1 -> l>0
    nt_store4(&out4[512 + c],
              make_float4(a0.x * inv, a0.y * inv, a0.z * inv, a0.w * inv));
    nt_store4(&out4[512 + c + 64],
              make_float4(a1.x * inv, a1.y * inv, a1.z * inv, a1.w * inv));
    nt_store4(&out4[512 + c + 128],
              make_float4(a2.x * inv, a2.y * inv, a2.z * inv, a2.w * inv));
    nt_store4(&out4[512 + c + 192],
              make_float4(a3.x * inv, a3.y * inv, a3.z * inv, a3.w * inv));
}

extern "C" void kernel_launch(void* const* d_in, const int* in_sizes, int n_in,
                              void* d_out, int out_size, void* d_ws, size_t ws_size,
                              hipStream_t stream) {
    const float* emb    = (const float*)d_in[0];
    const int*   starts = (const int*)d_in[1];
    const int*   ends   = (const int*)d_in[2];
    const float* attn_w = (const float*)d_in[3];
    const float* attn_b = (const float*)d_in[4];
    float* out = (float*)d_out;

    int* perm = (int*)d_ws;             // 4096 ints = 16 KB of workspace

    sort_spans_kernel<<<1, 1024, 0, stream>>>(starts, perm);
    span_repr_kernel<<<NBLK, 256, 0, stream>>>(emb, starts, ends, attn_w, attn_b, perm, out);
}

// Round 3
// 111.642 us; speedup vs baseline: 1.1199x; 1.0119x over previous
//
#include <hip/hip_runtime.h>
#include <math.h>

#define SEQ_LEN   8192
#define HIDDEN    1024
#define NUM_SPANS 4096
#define MAX_W     32
#define NBLK2     2048              // main kernel: 2 spans per block
#define NXCD      8

typedef float f4v __attribute__((ext_vector_type(4)));

__device__ __forceinline__ float dot4(float4 a, float4 b) {
    return a.x * b.x + a.y * b.y + a.z * b.z + a.w * b.w;
}

// Non-temporal 16B store: output (50 MB) is never re-read; keep it out of
// L2/L3 so embedding rows stay resident.
__device__ __forceinline__ void nt_store4(float4* p, float4 v) {
    f4v x = { v.x, v.y, v.z, v.w };
    __builtin_nontemporal_store(x, (f4v*)p);
}

// ---------------------------------------------------------------------------
// Prep kernel (one launch, independent blocks):
//   blocks 0..511  : scores[pos] = dot(emb[pos], attn_w) + bias for all 8192
//                    rows (16 waves/block, one wave per row). Scores are
//                    SPAN-INVARIANT -- round-3 insight: computing them per
//                    span-row (67K times) put a 16-FMA dot + 6-shfl butterfly
//                    + exp inside the serial row loop; 8192 precomputed
//                    scores delete all of it.
//   block 512      : counting sort of span ids by start (1024 buckets of 8
//                    rows) -- proven round 2: sorted span order is what fixed
//                    L2 locality (48 us -> ~30 us).
// ---------------------------------------------------------------------------
__global__ __launch_bounds__(1024) void prep_kernel(
    const int* __restrict__ starts,
    const float* __restrict__ emb,
    const float* __restrict__ attn_w,
    const float* __restrict__ attn_b,
    int* __restrict__ perm,             // (NUM_SPANS,)
    float* __restrict__ scores)         // (SEQ_LEN,)
{
    const int tid  = threadIdx.x;
    const int lane = tid & 63;
    const int wid  = tid >> 6;

    if (blockIdx.x < 512) {
        // ---- scores: one wave per row ----
        const int row = (blockIdx.x << 4) + wid;
        const float4* __restrict__ wv4 = (const float4*)attn_w;
        const float4 wv0 = wv4[lane];
        const float4 wv1 = wv4[lane + 64];
        const float4 wv2 = wv4[lane + 128];
        const float4 wv3 = wv4[lane + 192];
        const float4* __restrict__ rp = (const float4*)emb + (size_t)row * 256;
        float p = dot4(rp[lane],       wv0) + dot4(rp[lane + 64],  wv1)
                + dot4(rp[lane + 128], wv2) + dot4(rp[lane + 192], wv3);
        #pragma unroll
        for (int off = 32; off > 0; off >>= 1)
            p += __shfl_xor(p, off, 64);
        if (lane == 0) scores[row] = p + attn_b[0];
        return;
    }

    // ---- counting sort by start ----
    __shared__ int hist[1024];
    __shared__ int base[1024];
    __shared__ int wsum[16];

    hist[tid] = 0;
    __syncthreads();

    #pragma unroll
    for (int i = tid; i < NUM_SPANS; i += 1024)
        atomicAdd(&hist[starts[i] >> 3], 1);
    __syncthreads();

    const int v = hist[tid];
    int sc = v;
    #pragma unroll
    for (int off = 1; off < 64; off <<= 1) {
        const int t = __shfl_up(sc, off, 64);
        if (lane >= off) sc += t;
    }
    if (lane == 63) wsum[wid] = sc;
    __syncthreads();
    if (wid == 0 && lane < 16) {
        int ws = wsum[lane];
        #pragma unroll
        for (int off = 1; off < 16; off <<= 1) {
            const int t = __shfl_up(ws, off, 64);
            if (lane >= off) ws += t;
        }
        wsum[lane] = ws;                 // inclusive wave sums
    }
    __syncthreads();
    const int waveOff = (wid == 0) ? 0 : wsum[wid - 1];
    base[tid] = waveOff + sc - v;        // exclusive prefix for bucket tid
    __syncthreads();

    hist[tid] = 0;                       // reuse as per-bucket counters
    __syncthreads();

    #pragma unroll
    for (int i = tid; i < NUM_SPANS; i += 1024) {
        const int b   = starts[i] >> 3;
        const int pos = base[b] + atomicAdd(&hist[b], 1);
        perm[pos] = i;
    }
}

// ---------------------------------------------------------------------------
// Main kernel: TWO waves per span (each wave owns 512 columns = 2 float4 per
// lane), 2 spans per 256-thread block -> 2048 blocks = 32 waves/CU resident
// (was 16; measured OccupancyPercent 26). Sorted span order + XCD-contiguous
// slot mapping keeps each XCD's working set ~4 MB ~= its private L2.
// Weights are computed ONCE before the row loop from precomputed scores
// (lane-parallel: lane c holds score of span row c), so the row loop is just
//   load 2xfloat4, wr = broadcast(wt, r), acc += wr * v
// -- no dot, no butterfly, no exp, no rescale, no LDS, no barriers.
// ---------------------------------------------------------------------------
__global__ __launch_bounds__(256, 8) void span_repr_kernel(
    const float* __restrict__ emb,      // (SEQ_LEN, HIDDEN)
    const int* __restrict__ starts,     // (NUM_SPANS,)
    const int* __restrict__ ends,       // (NUM_SPANS,)
    const int* __restrict__ perm,       // (NUM_SPANS,) sorted span order
    const float* __restrict__ scores,   // (SEQ_LEN,) precomputed row scores
    float* __restrict__ out)            // (NUM_SPANS, 3*HIDDEN)
{
    const int tid = threadIdx.x;
    const int w2  = tid >> 6;           // wave id 0..3
    const int c   = tid & 63;           // lane

    // XCD-contiguous sorted slot; 2 spans per block, wave pair per span
    const int slot = (blockIdx.x & (NXCD - 1)) * (NBLK2 / NXCD) + (blockIdx.x >> 3);
    const int s    = perm[(slot << 1) + (w2 >> 1)];
    const int h    = w2 & 1;            // column half: f4 indices h*128 + [0,128)

    const int start = starts[s];
    const int wmax  = ends[s] - start;  // inclusive width-1, 0..31

    // ---- softmax weights from precomputed scores (outside the row loop) ----
    const float sc = (c <= wmax) ? scores[start + c] : -INFINITY;  // wmax<32
    float mx = sc;
    #pragma unroll
    for (int off = 32; off > 0; off >>= 1)
        mx = fmaxf(mx, __shfl_xor(mx, off, 64));
    const float e = (c <= wmax) ? __expf(sc - mx) : 0.0f;
    float sum = e;
    #pragma unroll
    for (int off = 32; off > 0; off >>= 1)
        sum += __shfl_xor(sum, off, 64);
    const float wt = e / sum;           // lane c: weight of span row c

    const float4* __restrict__ embr = (const float4*)emb + (size_t)start * 256 + (h << 7);
    float4* __restrict__ out4 = (float4*)(out + (size_t)s * (3 * HIDDEN)) + (h << 7);

    // row 0 == start row
    float4 v0 = embr[c];
    float4 v1 = embr[c + 64];
    nt_store4(&out4[c],      v0);
    nt_store4(&out4[c + 64], v1);

    const float w0 = __shfl(wt, 0, 64);
    float4 a0 = make_float4(w0 * v0.x, w0 * v0.y, w0 * v0.z, w0 * v0.w);
    float4 a1 = make_float4(w0 * v1.x, w0 * v1.y, w0 * v1.z, w0 * v1.w);

    // 1-deep pipeline; p enters holding row min(1,wmax) so that after the
    // loop p always holds row wmax (== end row), including wmax==0.
    const float4* nr = embr + (size_t)min(1, wmax) * 256;
    float4 p0 = nr[c];
    float4 p1 = nr[c + 64];

    for (int r = 1; r <= wmax; ++r) {
        const float4* __restrict__ xr = embr + (size_t)min(r + 1, wmax) * 256;
        float4 n0 = xr[c];
        float4 n1 = xr[c + 64];
        __builtin_amdgcn_sched_barrier(0);   // pin loads above the compute

        const float wr = __shfl(wt, r, 64);
        a0.x += wr * p0.x; a0.y += wr * p0.y; a0.z += wr * p0.z; a0.w += wr * p0.w;
        a1.x += wr * p1.x; a1.y += wr * p1.y; a1.z += wr * p1.z; a1.w += wr * p1.w;

        p0 = n0; p1 = n1;
    }

    // p holds row wmax == end row
    nt_store4(&out4[256 + c],      p0);
    nt_store4(&out4[256 + c + 64], p1);

    // weights are pre-normalized -> acc is the final attention output
    nt_store4(&out4[512 + c],      a0);
    nt_store4(&out4[512 + c + 64], a1);
}

extern "C" void kernel_launch(void* const* d_in, const int* in_sizes, int n_in,
                              void* d_out, int out_size, void* d_ws, size_t ws_size,
                              hipStream_t stream) {
    const float* emb    = (const float*)d_in[0];
    const int*   starts = (const int*)d_in[1];
    const int*   ends   = (const int*)d_in[2];
    const float* attn_w = (const float*)d_in[3];
    const float* attn_b = (const float*)d_in[4];
    float* out = (float*)d_out;

    int*   perm   = (int*)d_ws;                  // 4096 ints  = 16 KB
    float* scores = (float*)((int*)d_ws + NUM_SPANS);  // 8192 floats = 32 KB

    prep_kernel<<<513, 1024, 0, stream>>>(starts, emb, attn_w, attn_b, perm, scores);
    span_repr_kernel<<<NBLK2, 256, 0, stream>>>(emb, starts, ends, perm, scores, out);
}

// Round 4
// 107.634 us; speedup vs baseline: 1.1615x; 1.0372x over previous
//
#include <hip/hip_runtime.h>
#include <math.h>

#define SEQ_LEN   8192
#define HIDDEN    1024
#define NUM_SPANS 4096
#define MAX_W     32
#define NBLK2     2048              // main kernel: 2 spans per block
#define NXCD      8

typedef float f4v __attribute__((ext_vector_type(4)));

__device__ __forceinline__ float dot4(float4 a, float4 b) {
    return a.x * b.x + a.y * b.y + a.z * b.z + a.w * b.w;
}

// Non-temporal 16B store: output (50 MB) is never re-read; keep it out of
// L2/L3 so embedding rows stay resident.
__device__ __forceinline__ void nt_store4(float4* p, float4 v) {
    f4v x = { v.x, v.y, v.z, v.w };
    __builtin_nontemporal_store(x, (f4v*)p);
}

// ---------------------------------------------------------------------------
// Prep kernel. Round-4 changes, both on the prep<->main critical path:
//   * sort block moved to blockIdx 0 (was 512: with 256 CUs it started in the
//     THIRD dispatch round, serializing ~3 us of nearly-idle machine).
//   * score blocks are XCD-ALIGNED with the main kernel's row usage: main
//     gives XCD x the sorted spans [512x, 512(x+1)) -> rows ~[1024x,1024(x+1)).
//     Placing the score block for row-chunk k of XCD-range x at
//     blockIdx % 8 == x means prep's compulsory HBM read of the table lands
//     in exactly the L2 that main's blocks will re-read (4.2 MB/XCD) --
//     the round-2 locality lever applied to the prep->main handoff.
// Scores are span-invariant (round-3): one wave computes one row's
// dot(emb[row], attn_w) + bias; 8192 scores replace 67K in-loop dots.
// ---------------------------------------------------------------------------
__global__ __launch_bounds__(1024) void prep_kernel(
    const int* __restrict__ starts,
    const float* __restrict__ emb,
    const float* __restrict__ attn_w,
    const float* __restrict__ attn_b,
    int* __restrict__ perm,             // (NUM_SPANS,)
    float* __restrict__ scores)         // (SEQ_LEN,)
{
    const int tid  = threadIdx.x;
    const int lane = tid & 63;
    const int wid  = tid >> 6;

    if (blockIdx.x != 0) {
        // ---- scores: one wave per row, XCD-aligned row mapping ----
        const int x = blockIdx.x & 7;                     // this block's XCD
        const int k = (blockIdx.x >> 3) - (x == 0 ? 1 : 0); // chunk 0..63 in XCD range
        const int row = x * 1024 + k * 16 + wid;          // 16 rows per block
        const float4* __restrict__ wv4 = (const float4*)attn_w;
        const float4 wv0 = wv4[lane];
        const float4 wv1 = wv4[lane + 64];
        const float4 wv2 = wv4[lane + 128];
        const float4 wv3 = wv4[lane + 192];
        const float4* __restrict__ rp = (const float4*)emb + (size_t)row * 256;
        float p = dot4(rp[lane],       wv0) + dot4(rp[lane + 64],  wv1)
                + dot4(rp[lane + 128], wv2) + dot4(rp[lane + 192], wv3);
        #pragma unroll
        for (int off = 32; off > 0; off >>= 1)
            p += __shfl_xor(p, off, 64);
        if (lane == 0) scores[row] = p + attn_b[0];
        return;
    }

    // ---- blockIdx 0: counting sort of span ids by start (1024 buckets) ----
    __shared__ int hist[1024];
    __shared__ int base[1024];
    __shared__ int wsum[16];

    hist[tid] = 0;
    __syncthreads();

    #pragma unroll
    for (int i = tid; i < NUM_SPANS; i += 1024)
        atomicAdd(&hist[starts[i] >> 3], 1);
    __syncthreads();

    const int v = hist[tid];
    int sc = v;
    #pragma unroll
    for (int off = 1; off < 64; off <<= 1) {
        const int t = __shfl_up(sc, off, 64);
        if (lane >= off) sc += t;
    }
    if (lane == 63) wsum[wid] = sc;
    __syncthreads();
    if (wid == 0 && lane < 16) {
        int ws = wsum[lane];
        #pragma unroll
        for (int off = 1; off < 16; off <<= 1) {
            const int t = __shfl_up(ws, off, 64);
            if (lane >= off) ws += t;
        }
        wsum[lane] = ws;                 // inclusive wave sums
    }
    __syncthreads();
    const int waveOff = (wid == 0) ? 0 : wsum[wid - 1];
    base[tid] = waveOff + sc - v;        // exclusive prefix for bucket tid
    __syncthreads();

    hist[tid] = 0;                       // reuse as per-bucket counters
    __syncthreads();

    #pragma unroll
    for (int i = tid; i < NUM_SPANS; i += 1024) {
        const int b   = starts[i] >> 3;
        const int pos = base[b] + atomicAdd(&hist[b], 1);
        perm[pos] = i;
    }
}

// ---------------------------------------------------------------------------
// Main kernel (unchanged from round 3): two waves per span (each owns 512
// columns), 2 spans per block -> 2048 blocks, 32 waves/CU. Sorted span order
// + XCD-contiguous slot mapping keeps each XCD's working set ~4.2 MB in its
// private L2 (now pre-warmed by prep). Softmax weights computed once before
// the row loop from precomputed scores; the row loop is
//   load 2xfloat4, wr = broadcast(wt, r), acc += wr * v
// with a 1-deep register pipeline -- no LDS, no barriers.
// ---------------------------------------------------------------------------
__global__ __launch_bounds__(256, 8) void span_repr_kernel(
    const float* __restrict__ emb,      // (SEQ_LEN, HIDDEN)
    const int* __restrict__ starts,     // (NUM_SPANS,)
    const int* __restrict__ ends,       // (NUM_SPANS,)
    const int* __restrict__ perm,       // (NUM_SPANS,) sorted span order
    const float* __restrict__ scores,   // (SEQ_LEN,) precomputed row scores
    float* __restrict__ out)            // (NUM_SPANS, 3*HIDDEN)
{
    const int tid = threadIdx.x;
    const int w2  = tid >> 6;           // wave id 0..3
    const int c   = tid & 63;           // lane

    // XCD-contiguous sorted slot; 2 spans per block, wave pair per span
    const int slot = (blockIdx.x & (NXCD - 1)) * (NBLK2 / NXCD) + (blockIdx.x >> 3);
    const int s    = perm[(slot << 1) + (w2 >> 1)];
    const int h    = w2 & 1;            // column half: f4 indices h*128 + [0,128)

    const int start = starts[s];
    const int wmax  = ends[s] - start;  // inclusive width-1, 0..31

    // ---- softmax weights from precomputed scores (outside the row loop) ----
    const float sc = (c <= wmax) ? scores[start + c] : -INFINITY;  // wmax<32
    float mx = sc;
    #pragma unroll
    for (int off = 32; off > 0; off >>= 1)
        mx = fmaxf(mx, __shfl_xor(mx, off, 64));
    const float e = (c <= wmax) ? __expf(sc - mx) : 0.0f;
    float sum = e;
    #pragma unroll
    for (int off = 32; off > 0; off >>= 1)
        sum += __shfl_xor(sum, off, 64);
    const float wt = e / sum;           // lane c: weight of span row c

    const float4* __restrict__ embr = (const float4*)emb + (size_t)start * 256 + (h << 7);
    float4* __restrict__ out4 = (float4*)(out + (size_t)s * (3 * HIDDEN)) + (h << 7);

    // row 0 == start row
    float4 v0 = embr[c];
    float4 v1 = embr[c + 64];
    nt_store4(&out4[c],      v0);
    nt_store4(&out4[c + 64], v1);

    const float w0 = __shfl(wt, 0, 64);
    float4 a0 = make_float4(w0 * v0.x, w0 * v0.y, w0 * v0.z, w0 * v0.w);
    float4 a1 = make_float4(w0 * v1.x, w0 * v1.y, w0 * v1.z, w0 * v1.w);

    // 1-deep pipeline; p enters holding row min(1,wmax) so that after the
    // loop p always holds row wmax (== end row), including wmax==0.
    const float4* nr = embr + (size_t)min(1, wmax) * 256;
    float4 p0 = nr[c];
    float4 p1 = nr[c + 64];

    for (int r = 1; r <= wmax; ++r) {
        const float4* __restrict__ xr = embr + (size_t)min(r + 1, wmax) * 256;
        float4 n0 = xr[c];
        float4 n1 = xr[c + 64];
        __builtin_amdgcn_sched_barrier(0);   // pin loads above the compute

        const float wr = __shfl(wt, r, 64);
        a0.x += wr * p0.x; a0.y += wr * p0.y; a0.z += wr * p0.z; a0.w += wr * p0.w;
        a1.x += wr * p1.x; a1.y += wr * p1.y; a1.z += wr * p1.z; a1.w += wr * p1.w;

        p0 = n0; p1 = n1;
    }

    // p holds row wmax == end row
    nt_store4(&out4[256 + c],      p0);
    nt_store4(&out4[256 + c + 64], p1);

    // weights are pre-normalized -> acc is the final attention output
    nt_store4(&out4[512 + c],      a0);
    nt_store4(&out4[512 + c + 64], a1);
}

extern "C" void kernel_launch(void* const* d_in, const int* in_sizes, int n_in,
                              void* d_out, int out_size, void* d_ws, size_t ws_size,
                              hipStream_t stream) {
    const float* emb    = (const float*)d_in[0];
    const int*   starts = (const int*)d_in[1];
    const int*   ends   = (const int*)d_in[2];
    const float* attn_w = (const float*)d_in[3];
    const float* attn_b = (const float*)d_in[4];
    float* out = (float*)d_out;

    int*   perm   = (int*)d_ws;                        // 4096 ints  = 16 KB
    float* scores = (float*)((int*)d_ws + NUM_SPANS);  // 8192 floats = 32 KB

    prep_kernel<<<513, 1024, 0, stream>>>(starts, emb, attn_w, attn_b, perm, scores);
    span_repr_kernel<<<NBLK2, 256, 0, stream>>>(emb, starts, ends, perm, scores, out);
}